// Round 1
// baseline (73.927 us; speedup 1.0000x reference)
//
#include <hip/hip_runtime.h>
#include <hip/hip_bf16.h>

typedef _Float16 f16x8 __attribute__((ext_vector_type(8)));
typedef float    f32x4 __attribute__((ext_vector_type(4)));

constexpr int BB = 4;
constexpr int CH = 128;
constexpr int PC = 64;
constexpr int NN = 4096;

// ---------------------------------------------------------------------------
// Kernel 1: 1x1-conv projections via MFMA.
//   pos   = Wp @ pos_bot + bp   -> quantize to f16 x~ (workspace) + sq = ||x~||^2
//   value = Wv @ corr    + bv   -> equation_F (f32, [B,N,128])
// One wave handles 16 positions (n) and all output channels.
// A/B fragment packing convention (identical for both operands, so any
// internal k-permutation cancels): element e of lane l = M[base + (l&15)][k0 + (l>>4)*8 + e]
// C/D (m89-verified): col = lane&15, row = (lane>>4)*4 + reg.
// ---------------------------------------------------------------------------
__global__ __launch_bounds__(256) void proj_kernel(
    const float* __restrict__ pos_bot,  // [B,64,N]
    const float* __restrict__ corr,     // [B,128,N]
    const float* __restrict__ Wp,       // [64,64]
    const float* __restrict__ bp,       // [64]
    const float* __restrict__ Wv,       // [128,128]
    const float* __restrict__ bv,       // [128]
    float*    __restrict__ eqF,         // [B,N,128]
    _Float16* __restrict__ xbuf,        // [B,N,64] f16
    float*    __restrict__ sq)          // [B,N]
{
    const int tid  = threadIdx.x;
    const int wid  = tid >> 6;
    const int lane = tid & 63;
    const int l15  = lane & 15;
    const int lg   = lane >> 4;          // 0..3
    const int b    = blockIdx.y;
    const int nb   = blockIdx.x * 64 + wid * 16;
    const int n    = nb + l15;

    const f32x4 zero = {0.f, 0.f, 0.f, 0.f};

    // ---------------- pos projection ----------------
    f16x8 wf[4][2];
#pragma unroll
    for (int mt = 0; mt < 4; ++mt)
#pragma unroll
        for (int ks = 0; ks < 2; ++ks) {
            const float* wp = Wp + (mt * 16 + l15) * PC + ks * 32 + lg * 8;
            f32x4 w0 = *reinterpret_cast<const f32x4*>(wp);
            f32x4 w1 = *reinterpret_cast<const f32x4*>(wp + 4);
            f16x8 f;
#pragma unroll
            for (int e = 0; e < 4; ++e) { f[e] = (_Float16)w0[e]; f[e + 4] = (_Float16)w1[e]; }
            wf[mt][ks] = f;
        }

    f16x8 pb[2];
#pragma unroll
    for (int ks = 0; ks < 2; ++ks) {
        f16x8 f;
#pragma unroll
        for (int e = 0; e < 8; ++e) {
            const int c = ks * 32 + lg * 8 + e;
            f[e] = (_Float16)pos_bot[((size_t)(b * PC + c)) * NN + n];
        }
        pb[ks] = f;
    }

    f32x4 pacc[4] = {zero, zero, zero, zero};
#pragma unroll
    for (int ks = 0; ks < 2; ++ks)
#pragma unroll
        for (int mt = 0; mt < 4; ++mt)
            pacc[mt] = __builtin_amdgcn_mfma_f32_16x16x32_f16(wf[mt][ks], pb[ks], pacc[mt], 0, 0, 0);

    float sqp = 0.f;
#pragma unroll
    for (int mt = 0; mt < 4; ++mt)
#pragma unroll
        for (int r = 0; r < 4; ++r) {
            const int o = mt * 16 + lg * 4 + r;
            const float v = pacc[mt][r] + bp[o];
            const _Float16 h = (_Float16)v;             // the quantized x~ everyone uses
            xbuf[((size_t)(b * NN + n)) * PC + o] = h;
            const float hf = (float)h;
            sqp = fmaf(hf, hf, sqp);
        }
    sqp += __shfl_xor(sqp, 16);
    sqp += __shfl_xor(sqp, 32);
    if (lg == 0) sq[b * NN + n] = sqp;

    // ---------------- value projection ----------------
    f16x8 cb[4];
#pragma unroll
    for (int ks = 0; ks < 4; ++ks) {
        f16x8 f;
#pragma unroll
        for (int e = 0; e < 8; ++e) {
            const int c = ks * 32 + lg * 8 + e;
            f[e] = (_Float16)corr[((size_t)(b * CH + c)) * NN + n];
        }
        cb[ks] = f;
    }

#pragma unroll
    for (int oh = 0; oh < 2; ++oh) {
        f16x8 wvf[4][4];
#pragma unroll
        for (int mt = 0; mt < 4; ++mt)
#pragma unroll
            for (int ks = 0; ks < 4; ++ks) {
                const float* wv = Wv + (oh * 64 + mt * 16 + l15) * CH + ks * 32 + lg * 8;
                f32x4 w0 = *reinterpret_cast<const f32x4*>(wv);
                f32x4 w1 = *reinterpret_cast<const f32x4*>(wv + 4);
                f16x8 f;
#pragma unroll
                for (int e = 0; e < 4; ++e) { f[e] = (_Float16)w0[e]; f[e + 4] = (_Float16)w1[e]; }
                wvf[mt][ks] = f;
            }

        f32x4 vacc[4] = {zero, zero, zero, zero};
#pragma unroll
        for (int ks = 0; ks < 4; ++ks)
#pragma unroll
            for (int mt = 0; mt < 4; ++mt)
                vacc[mt] = __builtin_amdgcn_mfma_f32_16x16x32_f16(wvf[mt][ks], cb[ks], vacc[mt], 0, 0, 0);

#pragma unroll
        for (int mt = 0; mt < 4; ++mt)
#pragma unroll
            for (int r = 0; r < 4; ++r) {
                const int o = oh * 64 + mt * 16 + lg * 4 + r;
                eqF[((size_t)(b * NN + n)) * CH + o] = vacc[mt][r] + bv[o];
            }
    }
}

// ---------------------------------------------------------------------------
// Kernel 2: gram + RBF.  kernel[b,i,j] = exp(-beta * max(sq_i + sq_j - 2 x_i.x_j, 0))
// Block = 256 threads = 4 waves (2x2), block tile 128x128, wave tile 64x64.
// x is only 512 KB per b -> L2-resident; load fragments straight from global.
// This kernel is HBM-WRITE-bound (268 MB of output).
// ---------------------------------------------------------------------------
__global__ __launch_bounds__(256) void gram_kernel(
    const _Float16* __restrict__ xbuf,  // [B,N,64] f16
    const float*    __restrict__ sq,    // [B,N]
    const float*    __restrict__ beta,  // [1]
    float*          __restrict__ out)   // [B,N,N]
{
    const int tid  = threadIdx.x;
    const int wid  = tid >> 6;
    const int lane = tid & 63;
    const int l15  = lane & 15;
    const int lg   = lane >> 4;
    const int wr   = wid >> 1;
    const int wc   = wid & 1;
    const int b    = blockIdx.z;
    const int ib   = blockIdx.x * 128 + wr * 64;
    const int jb   = blockIdx.y * 128 + wc * 64;

    const _Float16* xb = xbuf + (size_t)b * NN * PC;
    const f32x4 zero = {0.f, 0.f, 0.f, 0.f};

    f16x8 af[4][2], bf[4][2];
#pragma unroll
    for (int t = 0; t < 4; ++t)
#pragma unroll
        for (int ks = 0; ks < 2; ++ks) {
            af[t][ks] = *reinterpret_cast<const f16x8*>(
                xb + (size_t)(ib + t * 16 + l15) * PC + ks * 32 + lg * 8);
            bf[t][ks] = *reinterpret_cast<const f16x8*>(
                xb + (size_t)(jb + t * 16 + l15) * PC + ks * 32 + lg * 8);
        }

    f32x4 acc[4][4];
#pragma unroll
    for (int it = 0; it < 4; ++it)
#pragma unroll
        for (int jt = 0; jt < 4; ++jt) acc[it][jt] = zero;

#pragma unroll
    for (int ks = 0; ks < 2; ++ks)
#pragma unroll
        for (int it = 0; it < 4; ++it)
#pragma unroll
            for (int jt = 0; jt < 4; ++jt)
                acc[it][jt] = __builtin_amdgcn_mfma_f32_16x16x32_f16(
                    af[it][ks], bf[jt][ks], acc[it][jt], 0, 0, 0);

    const float* sqb = sq + (size_t)b * NN;
    float sqj[4];
#pragma unroll
    for (int jt = 0; jt < 4; ++jt) sqj[jt] = sqb[jb + jt * 16 + l15];

    const float bs = -beta[0] * 1.44269504088896f;  // exp(-beta*d2) = exp2(bs*d2)

#pragma unroll
    for (int it = 0; it < 4; ++it) {
        float sqi[4];
#pragma unroll
        for (int r = 0; r < 4; ++r) sqi[r] = sqb[ib + it * 16 + lg * 4 + r];
#pragma unroll
        for (int jt = 0; jt < 4; ++jt) {
#pragma unroll
            for (int r = 0; r < 4; ++r) {
                float d2 = sqi[r] + sqj[jt] - 2.f * acc[it][jt][r];
                d2 = fmaxf(d2, 0.f);
                const float kv = __builtin_amdgcn_exp2f(bs * d2);
                const int i = ib + it * 16 + lg * 4 + r;
                const int j = jb + jt * 16 + l15;
                out[((size_t)(b * NN + i)) * NN + j] = kv;
            }
        }
    }
}

extern "C" void kernel_launch(void* const* d_in, const int* in_sizes, int n_in,
                              void* d_out, int out_size, void* d_ws, size_t ws_size,
                              hipStream_t stream) {
    const float* pos_bot = (const float*)d_in[0];
    const float* corr    = (const float*)d_in[1];
    const float* Wp      = (const float*)d_in[2];
    const float* bp      = (const float*)d_in[3];
    const float* Wv      = (const float*)d_in[4];
    const float* bv      = (const float*)d_in[5];
    const float* beta    = (const float*)d_in[6];

    float* out = (float*)d_out;                       // kernel [B,N,N]
    float* eqF = out + (size_t)BB * NN * NN;          // equation_F [B,N,128]

    _Float16* xbuf = (_Float16*)d_ws;                                  // 2 MB
    float* sq = (float*)((char*)d_ws + (size_t)BB * NN * PC * sizeof(_Float16));

    proj_kernel<<<dim3(NN / 64, BB), 256, 0, stream>>>(
        pos_bot, corr, Wp, bp, Wv, bv, eqF, xbuf, sq);

    gram_kernel<<<dim3(NN / 128, NN / 128, BB), 256, 0, stream>>>(
        xbuf, sq, beta, out);
}